// Round 5
// baseline (189.040 us; speedup 1.0000x reference)
//
#include <hip/hip_runtime.h>

// Expected output (deduced R0-R4): REAL PART of (Fr + i Fi) @ U as
// float32[65536, 128]; out_size = 8388608 (complex count), buffer 32 MB.
// Re(out) = Fr*Ur - Fi*Ui.  U = Clements mesh (128 layers of disjoint 2x2 MZI
// column rotations) * diag(e^{i oph}), built on-GPU, staged as bf16 MFMA
// B-fragments inside d_out (2 copies, bytes [0,128K) = rows 0..255).
//   k1 build_u:    128 blocks x 64 thr; block r evolves ROW r of U (rows are
//                  independent under column ops); writes both staging copies.
//   k2 cgemm_main: 510 blocks, rows 256..65535 (128-row tiles), reads copy A.
//   k3 cgemm_tail: 2 blocks; block b reads copy b -> LDS, syncthreads, then
//                  overwrites exactly that staging region (rows 128b..128b+127).

typedef __attribute__((ext_vector_type(8))) short short8;
typedef __attribute__((ext_vector_type(4))) float float4v;

#define MFMA(a, b, c) __builtin_amdgcn_mfma_f32_16x16x32_bf16((a), (b), (c), 0, 0, 0)

__device__ __forceinline__ unsigned short f2bf(float f) {
    unsigned u = __builtin_bit_cast(unsigned, f);
    u += 0x7FFFu + ((u >> 16) & 1u);   // round-to-nearest-even
    return (unsigned short)(u >> 16);
}

__device__ __forceinline__ short8 pack8(float4v a, float4v b) {
    short8 r;
    r[0] = (short)f2bf(a[0]); r[1] = (short)f2bf(a[1]);
    r[2] = (short)f2bf(a[2]); r[3] = (short)f2bf(a[3]);
    r[4] = (short)f2bf(b[0]); r[5] = (short)f2bf(b[1]);
    r[6] = (short)f2bf(b[2]); r[7] = (short)f2bf(b[3]);
    return r;
}

// ---------------- Kernel 1: build U, one block per row ----------------
__global__ __launch_bounds__(64) void build_u(
    const float* __restrict__ mzi, const float* __restrict__ oph,
    unsigned short* ufrag /* 2 copies x 2 planes x 16384 bf16, frag order */) {
    __shared__ float2 row[128];
    const int r = blockIdx.x;   // row of U this block owns
    const int p = threadIdx.x;  // lane = MZI pair index
    row[2 * p]     = make_float2((2 * p == r) ? 1.f : 0.f, 0.f);
    row[2 * p + 1] = make_float2((2 * p + 1 == r) ? 1.f : 0.f, 0.f);
    __syncthreads();
    for (int layer = 0; layer < 128; ++layer) {
        const int st  = layer & 1;
        const int idx = 127 * layer + st;  // phases consumed by prior layers
        if (p < 64 - st) {
            const int i = st + 2 * p;
            const float theta = mzi[idx + 2 * p];
            const float phi   = mzi[idx + 2 * p + 1];
            float s, c, sp, cp;
            sincosf(theta, &s, &c);
            sincosf(phi, &sp, &cp);
            // a = c*e^{i phi}; d = -c*conj(e^{i phi})
            const float ar = c * cp, ai = c * sp;
            const float2 u = row[i], v = row[i + 1];
            float2 nu, nv;
            nu.x = u.x * ar - u.y * ai + v.x * s;
            nu.y = u.x * ai + u.y * ar + v.y * s;
            nv.x = u.x * s - v.x * ar - v.y * ai;
            nv.y = u.y * s + v.x * ai - v.y * ar;
            row[i] = nu; row[i + 1] = nv;
        }
        __syncthreads();
    }
    // output-phase diagonal + bf16 + scatter into MFMA B-fragment order:
    // B[k][n]: nt=j>>4, lane=(j&15)|(((k>>3)&3)<<4), elem=k&7, kt=k>>5 (k=r,n=j)
    #pragma unroll
    for (int jj = 0; jj < 2; ++jj) {
        const int j = p + 64 * jj;
        const float2 v = row[j];
        float s, c;
        sincosf(oph[j], &s, &c);
        const unsigned short re = f2bf(v.x * c - v.y * s);
        const unsigned short im = f2bf(v.x * s + v.y * c);
        const int nt = j >> 4, kt = r >> 5;
        const int lane = (j & 15) | (((r >> 3) & 3) << 4);
        const int base = (nt * 4 + kt) * 512 + lane * 8 + (r & 7);
        ufrag[base]          = re;   // copy A, plane R
        ufrag[16384 + base]  = im;   // copy A, plane I
        ufrag[32768 + base]  = re;   // copy B, plane R
        ufrag[49152 + base]  = im;   // copy B, plane I
    }
}

// --------- 128-row tile, real-part GEMM (4 waves x 32 rows, N=K=128) ---------
__device__ __forceinline__ void gemm128(
    const float* __restrict__ fr, const float* __restrict__ fi,
    const unsigned short* ufcopy, float* out, int tilebase, int maxrow) {
    __shared__ __align__(16) unsigned short us[32768];  // 64 KB: Ur | Ui frags
    const int tid = threadIdx.x;
    {   // 64 KB global -> LDS: 256 thr x 16 iter x 16 B
        const uint4* g = (const uint4*)ufcopy;
        uint4* l = (uint4*)us;
        #pragma unroll
        for (int i = 0; i < 16; ++i) l[tid + 256 * i] = g[tid + 256 * i];
    }
    __syncthreads();

    const int wave = tid >> 6, lane = tid & 63;
    const int lm = lane & 15, lq = lane >> 4;
    const int rowbase = tilebase + wave * 32;

    float4v accR[2][8] = {};

    const size_t abase = (size_t)(rowbase + lm) * 128 + lq * 8;
    const float* pfr = fr + abase;   // mt adds 16 rows = +2048 floats
    const float* pfi = fi + abase;

    const short sgn = (short)0x8000;
    const short8 sgn8 = {sgn, sgn, sgn, sgn, sgn, sgn, sgn, sgn};

    float4v sr[2][2], si[2][2];
    #pragma unroll
    for (int mt = 0; mt < 2; ++mt) {
        sr[mt][0] = *(const float4v*)(pfr + mt * 2048);
        sr[mt][1] = *(const float4v*)(pfr + mt * 2048 + 4);
        si[mt][0] = *(const float4v*)(pfi + mt * 2048);
        si[mt][1] = *(const float4v*)(pfi + mt * 2048 + 4);
    }

    #pragma unroll
    for (int kt = 0; kt < 4; ++kt) {
        short8 afr[2], afin[2];
        #pragma unroll
        for (int mt = 0; mt < 2; ++mt) {
            afr[mt]  = pack8(sr[mt][0], sr[mt][1]);
            afin[mt] = pack8(si[mt][0], si[mt][1]) ^ sgn8;  // -Fi sign flip
        }
        if (kt < 3) {  // prefetch next k-tile while MFMAs run
            #pragma unroll
            for (int mt = 0; mt < 2; ++mt) {
                sr[mt][0] = *(const float4v*)(pfr + (kt + 1) * 32 + mt * 2048);
                sr[mt][1] = *(const float4v*)(pfr + (kt + 1) * 32 + mt * 2048 + 4);
                si[mt][0] = *(const float4v*)(pfi + (kt + 1) * 32 + mt * 2048);
                si[mt][1] = *(const float4v*)(pfi + (kt + 1) * 32 + mt * 2048 + 4);
            }
        }
        #pragma unroll
        for (int nt = 0; nt < 8; ++nt) {
            const int fo = (nt * 4 + kt) * 512 + lane * 8;
            const short8 ur = *(const short8*)&us[fo];
            const short8 ui = *(const short8*)&us[16384 + fo];
            #pragma unroll
            for (int mt = 0; mt < 2; ++mt) {
                accR[mt][nt] = MFMA(afr[mt],  ur, accR[mt][nt]);
                accR[mt][nt] = MFMA(afin[mt], ui, accR[mt][nt]);
            }
        }
    }

    // epilogue: D layout col = lane&15, row = (lane>>4)*4 + reg — GUARDED
    #pragma unroll
    for (int mt = 0; mt < 2; ++mt) {
        #pragma unroll
        for (int nt = 0; nt < 8; ++nt) {
            #pragma unroll
            for (int reg = 0; reg < 4; ++reg) {
                const int rr = rowbase + mt * 16 + lq * 4 + reg;
                if (rr < maxrow)
                    out[(size_t)rr * 128 + nt * 16 + lm] = accR[mt][nt][reg];
            }
        }
    }
}

__global__ __launch_bounds__(256, 2) void cgemm_main(
    const float* __restrict__ fr, const float* __restrict__ fi,
    const unsigned short* ufrag, float* out, int maxrow) {
    gemm128(fr, fi, ufrag, out, 256 + blockIdx.x * 128, maxrow);  // copy A
}

__global__ __launch_bounds__(256, 2) void cgemm_tail(
    const float* __restrict__ fr, const float* __restrict__ fi,
    const unsigned short* ufrag, float* out, int maxrow) {
    // block b reads copy b, overwrites exactly rows 128b..128b+127 (its bytes)
    gemm128(fr, fi, ufrag + blockIdx.x * 32768, out, blockIdx.x * 128, maxrow);
}

extern "C" void kernel_launch(void* const* d_in, const int* in_sizes, int n_in,
                              void* d_out, int out_size, void* d_ws, size_t ws_size,
                              hipStream_t stream) {
    const float* fr  = (const float*)d_in[0];
    const float* fi  = (const float*)d_in[1];
    const float* mzi = (const float*)d_in[2];
    const float* oph = (const float*)d_in[3];
    unsigned short* ufrag = (unsigned short*)d_out;  // staging inside d_out

    // Capacity in 128-float output rows; clamp by field rows (A-load safety).
    int maxrow = out_size / 128;
    const int arows = in_sizes[0] / 128;
    if (maxrow > arows) maxrow = arows;
    if (maxrow > 65536) maxrow = 65536;
    if (out_size < 32768 || maxrow < 256) return;  // need 128 KB staging room

    build_u<<<128, 64, 0, stream>>>(mzi, oph, ufrag);
    const int nmain = (maxrow - 256 + 127) / 128;
    if (nmain > 0)
        cgemm_main<<<nmain, 256, 0, stream>>>(fr, fi, ufrag, (float*)d_out, maxrow);
    cgemm_tail<<<2, 256, 0, stream>>>(fr, fi, ufrag, (float*)d_out, maxrow);
}

// Round 6
// 184.571 us; speedup vs baseline: 1.0242x; 1.0242x over previous
//
#include <hip/hip_runtime.h>

// out = Re[(Fr + i Fi) @ U] as float32[65536,128] (out_size = 8388608 floats).
// U = Clements mesh (128 layers of disjoint 2x2 MZI column rotations) * diag(e^{i oph}).
// Staging inside d_out: U bf16 MFMA B-frags, 2 copies, bytes [0,128K) = rows 0..255;
// trig table (8192 float4) at rows 256..511, overwritten by cgemm_main blocks 0-1.
//   k0 trig_k:     8128 MZIs -> (ct*cp, ct*sp, st) float4; pad to 8192 with zeros.
//   k1 build_u:    128 blocks x 1 wave; block r evolves ROW r of U entirely in
//                  registers (lane p holds cols 2p,2p+1); odd layers exchange the
//                  neighbor column via shfl (wave-synchronous, no barriers);
//                  trig via depth-8 global prefetch ring. Writes both staging copies.
//   k2 cgemm_main: 510 blocks, rows 256..65535 (128-row tiles), reads copy A.
//   k3 cgemm_tail: 2 blocks; block b reads copy b -> LDS, then overwrites exactly
//                  that staging region (rows 128b..128b+127).

typedef __attribute__((ext_vector_type(8))) short short8;
typedef __attribute__((ext_vector_type(4))) float float4v;

#define MFMA(a, b, c) __builtin_amdgcn_mfma_f32_16x16x32_bf16((a), (b), (c), 0, 0, 0)

__device__ __forceinline__ unsigned short f2bf(float f) {
    unsigned u = __builtin_bit_cast(unsigned, f);
    u += 0x7FFFu + ((u >> 16) & 1u);   // round-to-nearest-even
    return (unsigned short)(u >> 16);
}

__device__ __forceinline__ short8 pack8(float4v a, float4v b) {
    short8 r;
    r[0] = (short)f2bf(a[0]); r[1] = (short)f2bf(a[1]);
    r[2] = (short)f2bf(a[2]); r[3] = (short)f2bf(a[3]);
    r[4] = (short)f2bf(b[0]); r[5] = (short)f2bf(b[1]);
    r[6] = (short)f2bf(b[2]); r[7] = (short)f2bf(b[3]);
    return r;
}

// ---------------- Kernel 0: per-MZI trig (fully parallel) ----------------
__global__ __launch_bounds__(256) void trig_k(const float* __restrict__ mzi,
                                              float4* __restrict__ trig) {
    const int id = blockIdx.x * 256 + threadIdx.x;
    if (id >= 8192) return;
    if (id < 8128) {
        const float theta = mzi[2 * id], phi = mzi[2 * id + 1];
        float st, ct, sp, cp;
        sincosf(theta, &st, &ct);
        sincosf(phi, &sp, &cp);
        trig[id] = make_float4(ct * cp, ct * sp, st, 0.f);
    } else {
        trig[id] = make_float4(0.f, 0.f, 0.f, 0.f);  // pad (keeps ring loads in-bounds)
    }
}

// ---------------- Kernel 1: build U, one block (1 wave) per row ----------------
// MZI id for (layer l, pair p): (127*l + (l&1))/2 + p   (max 8128 -> padded buf)
__global__ __launch_bounds__(64) void build_u(
    const float* __restrict__ oph, const float4* __restrict__ trig,
    unsigned short* ufrag /* 2 copies x 2 planes x 16384 bf16, frag order */) {
    const int r = blockIdx.x;   // row of U this block owns
    const int p = threadIdx.x;  // lane: owns cols 2p, 2p+1
    float2 c0 = make_float2((2 * p == r) ? 1.f : 0.f, 0.f);
    float2 c1 = make_float2((2 * p + 1 == r) ? 1.f : 0.f, 0.f);

    float4 ring[8];
    #pragma unroll
    for (int i = 0; i < 8; ++i)
        ring[i] = trig[(127 * i + (i & 1)) / 2 + p];

    for (int l = 0; l < 128; ++l) {
        const float4 t = ring[l & 7];
        if (l + 8 < 128)
            ring[l & 7] = trig[(127 * (l + 8) + ((l + 8) & 1)) / 2 + p];
        const float ar = t.x, ai = t.y, s = t.z;
        if ((l & 1) == 0) {
            // pair (2p, 2p+1) = (c0, c1), fully local
            const float2 u = c0, v = c1;
            c0.x = u.x * ar - u.y * ai + v.x * s;
            c0.y = u.x * ai + u.y * ar + v.y * s;
            c1.x = u.x * s - v.x * ar - v.y * ai;
            c1.y = u.y * s + v.x * ai - v.y * ar;
        } else {
            // pair q=p: cols (2p+1, 2p+2) = (my c1, lane p+1's c0)
            const float vx = __shfl_down(c0.x, 1);
            const float vy = __shfl_down(c0.y, 1);
            const float2 u = c1;
            const float nux = u.x * ar - u.y * ai + vx * s;
            const float nuy = u.x * ai + u.y * ar + vy * s;
            const float nvx = u.x * s - vx * ar - vy * ai;
            const float nvy = u.y * s + vx * ai - vy * ar;
            if (p < 63) { c1.x = nux; c1.y = nuy; }   // col 2p+1 update
            const float bx = __shfl_up(nvx, 1);       // col 2p+2 -> lane p+1's c0
            const float by = __shfl_up(nvy, 1);
            if (p > 0) { c0.x = bx; c0.y = by; }      // lane 0 keeps col 0
        }
    }

    // output-phase diagonal + bf16 + scatter into MFMA B-fragment order:
    // B[k][n]: nt=j>>4, lane=(j&15)|(((k>>3)&3)<<4), elem=k&7, kt=k>>5 (k=r,n=j)
    #pragma unroll
    for (int jj = 0; jj < 2; ++jj) {
        const int j = 2 * p + jj;
        const float2 v = (jj == 0) ? c0 : c1;
        float s, c;
        sincosf(oph[j], &s, &c);
        const unsigned short re = f2bf(v.x * c - v.y * s);
        const unsigned short im = f2bf(v.x * s + v.y * c);
        const int nt = j >> 4, kt = r >> 5;
        const int lane = (j & 15) | (((r >> 3) & 3) << 4);
        const int base = (nt * 4 + kt) * 512 + lane * 8 + (r & 7);
        ufrag[base]          = re;   // copy A, plane R
        ufrag[16384 + base]  = im;   // copy A, plane I
        ufrag[32768 + base]  = re;   // copy B, plane R
        ufrag[49152 + base]  = im;   // copy B, plane I
    }
}

// --------- 128-row tile, real-part GEMM (4 waves x 32 rows, N=K=128) ---------
__device__ __forceinline__ void gemm128(
    const float* __restrict__ fr, const float* __restrict__ fi,
    const unsigned short* ufcopy, float* out, int tilebase, int maxrow) {
    __shared__ __align__(16) unsigned short us[32768];  // 64 KB: Ur | Ui frags
    const int tid = threadIdx.x;
    {   // 64 KB global -> LDS: 256 thr x 16 iter x 16 B
        const uint4* g = (const uint4*)ufcopy;
        uint4* l = (uint4*)us;
        #pragma unroll
        for (int i = 0; i < 16; ++i) l[tid + 256 * i] = g[tid + 256 * i];
    }
    __syncthreads();

    const int wave = tid >> 6, lane = tid & 63;
    const int lm = lane & 15, lq = lane >> 4;
    const int rowbase = tilebase + wave * 32;

    float4v accR[2][8] = {};

    const size_t abase = (size_t)(rowbase + lm) * 128 + lq * 8;
    const float* pfr = fr + abase;   // mt adds 16 rows = +2048 floats
    const float* pfi = fi + abase;

    const short sgn = (short)0x8000;
    const short8 sgn8 = {sgn, sgn, sgn, sgn, sgn, sgn, sgn, sgn};

    float4v sr[2][2], si[2][2];
    #pragma unroll
    for (int mt = 0; mt < 2; ++mt) {
        sr[mt][0] = *(const float4v*)(pfr + mt * 2048);
        sr[mt][1] = *(const float4v*)(pfr + mt * 2048 + 4);
        si[mt][0] = *(const float4v*)(pfi + mt * 2048);
        si[mt][1] = *(const float4v*)(pfi + mt * 2048 + 4);
    }

    #pragma unroll
    for (int kt = 0; kt < 4; ++kt) {
        short8 afr[2], afin[2];
        #pragma unroll
        for (int mt = 0; mt < 2; ++mt) {
            afr[mt]  = pack8(sr[mt][0], sr[mt][1]);
            afin[mt] = pack8(si[mt][0], si[mt][1]) ^ sgn8;  // -Fi sign flip
        }
        if (kt < 3) {  // prefetch next k-tile while MFMAs run
            #pragma unroll
            for (int mt = 0; mt < 2; ++mt) {
                sr[mt][0] = *(const float4v*)(pfr + (kt + 1) * 32 + mt * 2048);
                sr[mt][1] = *(const float4v*)(pfr + (kt + 1) * 32 + mt * 2048 + 4);
                si[mt][0] = *(const float4v*)(pfi + (kt + 1) * 32 + mt * 2048);
                si[mt][1] = *(const float4v*)(pfi + (kt + 1) * 32 + mt * 2048 + 4);
            }
        }
        #pragma unroll
        for (int nt = 0; nt < 8; ++nt) {
            const int fo = (nt * 4 + kt) * 512 + lane * 8;
            const short8 ur = *(const short8*)&us[fo];
            const short8 ui = *(const short8*)&us[16384 + fo];
            #pragma unroll
            for (int mt = 0; mt < 2; ++mt) {
                accR[mt][nt] = MFMA(afr[mt],  ur, accR[mt][nt]);
                accR[mt][nt] = MFMA(afin[mt], ui, accR[mt][nt]);
            }
        }
    }

    // epilogue: D layout col = lane&15, row = (lane>>4)*4 + reg — GUARDED
    #pragma unroll
    for (int mt = 0; mt < 2; ++mt) {
        #pragma unroll
        for (int nt = 0; nt < 8; ++nt) {
            #pragma unroll
            for (int reg = 0; reg < 4; ++reg) {
                const int rr = rowbase + mt * 16 + lq * 4 + reg;
                if (rr < maxrow)
                    out[(size_t)rr * 128 + nt * 16 + lm] = accR[mt][nt][reg];
            }
        }
    }
}

__global__ __launch_bounds__(256, 2) void cgemm_main(
    const float* __restrict__ fr, const float* __restrict__ fi,
    const unsigned short* ufrag, float* out, int maxrow) {
    gemm128(fr, fi, ufrag, out, 256 + blockIdx.x * 128, maxrow);  // copy A
}

__global__ __launch_bounds__(256, 2) void cgemm_tail(
    const float* __restrict__ fr, const float* __restrict__ fi,
    const unsigned short* ufrag, float* out, int maxrow) {
    // block b reads copy b, overwrites exactly rows 128b..128b+127 (its bytes)
    gemm128(fr, fi, ufrag + blockIdx.x * 32768, out, blockIdx.x * 128, maxrow);
}

extern "C" void kernel_launch(void* const* d_in, const int* in_sizes, int n_in,
                              void* d_out, int out_size, void* d_ws, size_t ws_size,
                              hipStream_t stream) {
    const float* fr  = (const float*)d_in[0];
    const float* fi  = (const float*)d_in[1];
    const float* mzi = (const float*)d_in[2];
    const float* oph = (const float*)d_in[3];
    unsigned short* ufrag = (unsigned short*)d_out;          // rows 0..255
    float4* trig = (float4*)((float*)d_out + 32768);         // rows 256..511

    // Capacity in 128-float output rows; clamp by field rows (A-load safety).
    int maxrow = out_size / 128;
    const int arows = in_sizes[0] / 128;
    if (maxrow > arows) maxrow = arows;
    if (maxrow > 65536) maxrow = 65536;
    if (maxrow < 512) return;  // need rows 0..511 for staging + trig

    trig_k<<<32, 256, 0, stream>>>(mzi, trig);
    build_u<<<128, 64, 0, stream>>>(oph, trig, ufrag);
    const int nmain = (maxrow - 256 + 127) / 128;
    cgemm_main<<<nmain, 256, 0, stream>>>(fr, fi, ufrag, (float*)d_out, maxrow);
    cgemm_tail<<<2, 256, 0, stream>>>(fr, fi, ufrag, (float*)d_out, maxrow);
}

// Round 7
// 131.673 us; speedup vs baseline: 1.4357x; 1.4017x over previous
//
#include <hip/hip_runtime.h>

// out = Re[(Fr + i Fi) @ U] as float32[65536,128] (out_size = 8388608 floats).
// U = Clements mesh (128 layers of disjoint 2x2 MZI column rotations) * diag(e^{i oph}).
// Staging inside d_out: U bf16 MFMA B-frags, 2 copies, bytes [0,128K) = rows 0..255;
// trig table (8192 float4) at rows 256..511, overwritten by cgemm_main blocks 0-1.
//   k0 trig_k:     8128 MZIs -> (ct*cp, ct*sp, st) float4; pad to 8192 with zeros.
//   k1 build_u:    128 blocks x 1 wave; block r evolves ROW r of U in registers
//                  (lane p holds cols 2p,2p+1); odd layers exchange neighbor
//                  column via shfl. FULL UNROLL so the depth-8 trig prefetch
//                  ring stays in VGPRs (R6: dynamic ring index -> scratch ->
//                  ~900 cyc/layer serial round-trips -> 62 us).
//   k2 cgemm_main: 510 blocks, rows 256..65535 (128-row tiles), reads copy A.
//   k3 cgemm_tail: 2 blocks; block b reads copy b -> LDS, then overwrites exactly
//                  that staging region (rows 128b..128b+127).

typedef __attribute__((ext_vector_type(8))) short short8;
typedef __attribute__((ext_vector_type(4))) float float4v;

#define MFMA(a, b, c) __builtin_amdgcn_mfma_f32_16x16x32_bf16((a), (b), (c), 0, 0, 0)

__device__ __forceinline__ unsigned short f2bf(float f) {
    unsigned u = __builtin_bit_cast(unsigned, f);
    u += 0x7FFFu + ((u >> 16) & 1u);   // round-to-nearest-even
    return (unsigned short)(u >> 16);
}

__device__ __forceinline__ short8 pack8(float4v a, float4v b) {
    short8 r;
    r[0] = (short)f2bf(a[0]); r[1] = (short)f2bf(a[1]);
    r[2] = (short)f2bf(a[2]); r[3] = (short)f2bf(a[3]);
    r[4] = (short)f2bf(b[0]); r[5] = (short)f2bf(b[1]);
    r[6] = (short)f2bf(b[2]); r[7] = (short)f2bf(b[3]);
    return r;
}

// ---------------- Kernel 0: per-MZI trig (fully parallel) ----------------
__global__ __launch_bounds__(256) void trig_k(const float* __restrict__ mzi,
                                              float4* __restrict__ trig) {
    const int id = blockIdx.x * 256 + threadIdx.x;
    if (id >= 8192) return;
    if (id < 8128) {
        const float theta = mzi[2 * id], phi = mzi[2 * id + 1];
        float st, ct, sp, cp;
        sincosf(theta, &st, &ct);
        sincosf(phi, &sp, &cp);
        trig[id] = make_float4(ct * cp, ct * sp, st, 0.f);
    } else {
        trig[id] = make_float4(0.f, 0.f, 0.f, 0.f);  // pad (keeps ring loads in-bounds)
    }
}

// ---------------- Kernel 1: build U, one block (1 wave) per row ----------------
// MZI id for (layer l, pair p): (127*l + (l&1))/2 + p   (max 8128 -> padded buf)
__global__ __launch_bounds__(64) void build_u(
    const float* __restrict__ oph, const float4* __restrict__ trig,
    unsigned short* ufrag /* 2 copies x 2 planes x 16384 bf16, frag order */) {
    const int r = blockIdx.x;   // row of U this block owns
    const int p = threadIdx.x;  // lane: owns cols 2p, 2p+1
    float2 c0 = make_float2((2 * p == r) ? 1.f : 0.f, 0.f);
    float2 c1 = make_float2((2 * p + 1 == r) ? 1.f : 0.f, 0.f);

    float4 ring[8];
    #pragma unroll
    for (int i = 0; i < 8; ++i)
        ring[i] = trig[(127 * i + (i & 1)) / 2 + p];

    #pragma unroll   // FULL unroll: ring indices become constants -> VGPRs
    for (int l = 0; l < 128; ++l) {
        const float4 t = ring[l & 7];
        if (l + 8 < 128)
            ring[l & 7] = trig[(127 * (l + 8) + ((l + 8) & 1)) / 2 + p];
        const float ar = t.x, ai = t.y, s = t.z;
        if ((l & 1) == 0) {
            // pair (2p, 2p+1) = (c0, c1), fully local
            const float2 u = c0, v = c1;
            c0.x = u.x * ar - u.y * ai + v.x * s;
            c0.y = u.x * ai + u.y * ar + v.y * s;
            c1.x = u.x * s - v.x * ar - v.y * ai;
            c1.y = u.y * s + v.x * ai - v.y * ar;
        } else {
            // pair q=p: cols (2p+1, 2p+2) = (my c1, lane p+1's c0)
            const float vx = __shfl_down(c0.x, 1);
            const float vy = __shfl_down(c0.y, 1);
            const float2 u = c1;
            const float nux = u.x * ar - u.y * ai + vx * s;
            const float nuy = u.x * ai + u.y * ar + vy * s;
            const float nvx = u.x * s - vx * ar - vy * ai;
            const float nvy = u.y * s + vx * ai - vy * ar;
            if (p < 63) { c1.x = nux; c1.y = nuy; }   // col 2p+1 update
            const float bx = __shfl_up(nvx, 1);       // col 2p+2 -> lane p+1's c0
            const float by = __shfl_up(nvy, 1);
            if (p > 0) { c0.x = bx; c0.y = by; }      // lane 0 keeps col 0
        }
    }

    // output-phase diagonal + bf16 + scatter into MFMA B-fragment order:
    // B[k][n]: nt=j>>4, lane=(j&15)|(((k>>3)&3)<<4), elem=k&7, kt=k>>5 (k=r,n=j)
    #pragma unroll
    for (int jj = 0; jj < 2; ++jj) {
        const int j = 2 * p + jj;
        const float2 v = (jj == 0) ? c0 : c1;
        float s, c;
        sincosf(oph[j], &s, &c);
        const unsigned short re = f2bf(v.x * c - v.y * s);
        const unsigned short im = f2bf(v.x * s + v.y * c);
        const int nt = j >> 4, kt = r >> 5;
        const int lane = (j & 15) | (((r >> 3) & 3) << 4);
        const int base = (nt * 4 + kt) * 512 + lane * 8 + (r & 7);
        ufrag[base]          = re;   // copy A, plane R
        ufrag[16384 + base]  = im;   // copy A, plane I
        ufrag[32768 + base]  = re;   // copy B, plane R
        ufrag[49152 + base]  = im;   // copy B, plane I
    }
}

// --------- 128-row tile, real-part GEMM (4 waves x 32 rows, N=K=128) ---------
__device__ __forceinline__ void gemm128(
    const float* __restrict__ fr, const float* __restrict__ fi,
    const unsigned short* ufcopy, float* out, int tilebase, int maxrow) {
    __shared__ __align__(16) unsigned short us[32768];  // 64 KB: Ur | Ui frags
    const int tid = threadIdx.x;
    {   // 64 KB global -> LDS: 256 thr x 16 iter x 16 B
        const uint4* g = (const uint4*)ufcopy;
        uint4* l = (uint4*)us;
        #pragma unroll
        for (int i = 0; i < 16; ++i) l[tid + 256 * i] = g[tid + 256 * i];
    }
    __syncthreads();

    const int wave = tid >> 6, lane = tid & 63;
    const int lm = lane & 15, lq = lane >> 4;
    const int rowbase = tilebase + wave * 32;

    float4v accR[2][8] = {};

    const size_t abase = (size_t)(rowbase + lm) * 128 + lq * 8;
    const float* pfr = fr + abase;   // mt adds 16 rows = +2048 floats
    const float* pfi = fi + abase;

    const short sgn = (short)0x8000;
    const short8 sgn8 = {sgn, sgn, sgn, sgn, sgn, sgn, sgn, sgn};

    float4v sr[2][2], si[2][2];
    #pragma unroll
    for (int mt = 0; mt < 2; ++mt) {
        sr[mt][0] = *(const float4v*)(pfr + mt * 2048);
        sr[mt][1] = *(const float4v*)(pfr + mt * 2048 + 4);
        si[mt][0] = *(const float4v*)(pfi + mt * 2048);
        si[mt][1] = *(const float4v*)(pfi + mt * 2048 + 4);
    }

    #pragma unroll
    for (int kt = 0; kt < 4; ++kt) {
        short8 afr[2], afin[2];
        #pragma unroll
        for (int mt = 0; mt < 2; ++mt) {
            afr[mt]  = pack8(sr[mt][0], sr[mt][1]);
            afin[mt] = pack8(si[mt][0], si[mt][1]) ^ sgn8;  // -Fi sign flip
        }
        if (kt < 3) {  // prefetch next k-tile while MFMAs run
            #pragma unroll
            for (int mt = 0; mt < 2; ++mt) {
                sr[mt][0] = *(const float4v*)(pfr + (kt + 1) * 32 + mt * 2048);
                sr[mt][1] = *(const float4v*)(pfr + (kt + 1) * 32 + mt * 2048 + 4);
                si[mt][0] = *(const float4v*)(pfi + (kt + 1) * 32 + mt * 2048);
                si[mt][1] = *(const float4v*)(pfi + (kt + 1) * 32 + mt * 2048 + 4);
            }
        }
        #pragma unroll
        for (int nt = 0; nt < 8; ++nt) {
            const int fo = (nt * 4 + kt) * 512 + lane * 8;
            const short8 ur = *(const short8*)&us[fo];
            const short8 ui = *(const short8*)&us[16384 + fo];
            #pragma unroll
            for (int mt = 0; mt < 2; ++mt) {
                accR[mt][nt] = MFMA(afr[mt],  ur, accR[mt][nt]);
                accR[mt][nt] = MFMA(afin[mt], ui, accR[mt][nt]);
            }
        }
    }

    // epilogue: D layout col = lane&15, row = (lane>>4)*4 + reg — GUARDED
    #pragma unroll
    for (int mt = 0; mt < 2; ++mt) {
        #pragma unroll
        for (int nt = 0; nt < 8; ++nt) {
            #pragma unroll
            for (int reg = 0; reg < 4; ++reg) {
                const int rr = rowbase + mt * 16 + lq * 4 + reg;
                if (rr < maxrow)
                    out[(size_t)rr * 128 + nt * 16 + lm] = accR[mt][nt][reg];
            }
        }
    }
}

__global__ __launch_bounds__(256, 2) void cgemm_main(
    const float* __restrict__ fr, const float* __restrict__ fi,
    const unsigned short* ufrag, float* out, int maxrow) {
    gemm128(fr, fi, ufrag, out, 256 + blockIdx.x * 128, maxrow);  // copy A
}

__global__ __launch_bounds__(256, 2) void cgemm_tail(
    const float* __restrict__ fr, const float* __restrict__ fi,
    const unsigned short* ufrag, float* out, int maxrow) {
    // block b reads copy b, overwrites exactly rows 128b..128b+127 (its bytes)
    gemm128(fr, fi, ufrag + blockIdx.x * 32768, out, blockIdx.x * 128, maxrow);
}

extern "C" void kernel_launch(void* const* d_in, const int* in_sizes, int n_in,
                              void* d_out, int out_size, void* d_ws, size_t ws_size,
                              hipStream_t stream) {
    const float* fr  = (const float*)d_in[0];
    const float* fi  = (const float*)d_in[1];
    const float* mzi = (const float*)d_in[2];
    const float* oph = (const float*)d_in[3];
    unsigned short* ufrag = (unsigned short*)d_out;          // rows 0..255
    float4* trig = (float4*)((float*)d_out + 32768);         // rows 256..511

    // Capacity in 128-float output rows; clamp by field rows (A-load safety).
    int maxrow = out_size / 128;
    const int arows = in_sizes[0] / 128;
    if (maxrow > arows) maxrow = arows;
    if (maxrow > 65536) maxrow = 65536;
    if (maxrow < 512) return;  // need rows 0..511 for staging + trig

    trig_k<<<32, 256, 0, stream>>>(mzi, trig);
    build_u<<<128, 64, 0, stream>>>(oph, trig, ufrag);
    const int nmain = (maxrow - 256 + 127) / 128;
    cgemm_main<<<nmain, 256, 0, stream>>>(fr, fi, ufrag, (float*)d_out, maxrow);
    cgemm_tail<<<2, 256, 0, stream>>>(fr, fi, ufrag, (float*)d_out, maxrow);
}

// Round 8
// 121.779 us; speedup vs baseline: 1.5523x; 1.0812x over previous
//
#include <hip/hip_runtime.h>

// out = Re[(Fr + i Fi) @ U] as float32[65536,128] (out_size = 8388608 floats).
// U = Clements mesh (128 layers of disjoint 2x2 MZI column rotations) * diag(e^{i oph}).
// R7 profile showed 256 MiB d_ws re-poison fills => ws_size ~256 MiB. Staging now
// lives in d_ws (R1-R3 crashes were d_out overruns, not d_ws): no tail kernel,
// one uniform cgemm over all 512 row-tiles. d_out fallback path kept if ws tiny.
//   k0 trig_k:   8128 MZIs -> (ct*cp, ct*sp, st) float4; pad to 8192.
//   k1 build_u:  128 blocks x 1 wave; block r evolves ROW r of U in registers
//                (lane p owns cols 2p,2p+1; odd layers shfl-exchange neighbor col;
//                depth-8 trig ring, FULL unroll keeps ring in VGPRs).
//   k2 cgemm:    512 blocks x 256 thr (4 waves x 32 rows), N=K=128, bf16 MFMA,
//                Re = Fr*Ur - Fi*Ui; U frags LDS-resident (64 KB).

typedef __attribute__((ext_vector_type(8))) short short8;
typedef __attribute__((ext_vector_type(4))) float float4v;

#define MFMA(a, b, c) __builtin_amdgcn_mfma_f32_16x16x32_bf16((a), (b), (c), 0, 0, 0)

__device__ __forceinline__ unsigned short f2bf(float f) {
    unsigned u = __builtin_bit_cast(unsigned, f);
    u += 0x7FFFu + ((u >> 16) & 1u);   // round-to-nearest-even
    return (unsigned short)(u >> 16);
}

__device__ __forceinline__ short8 pack8(float4v a, float4v b) {
    short8 r;
    r[0] = (short)f2bf(a[0]); r[1] = (short)f2bf(a[1]);
    r[2] = (short)f2bf(a[2]); r[3] = (short)f2bf(a[3]);
    r[4] = (short)f2bf(b[0]); r[5] = (short)f2bf(b[1]);
    r[6] = (short)f2bf(b[2]); r[7] = (short)f2bf(b[3]);
    return r;
}

// ---------------- Kernel 0: per-MZI trig (fully parallel) ----------------
__global__ __launch_bounds__(256) void trig_k(const float* __restrict__ mzi,
                                              float4* __restrict__ trig) {
    const int id = blockIdx.x * 256 + threadIdx.x;
    if (id >= 8192) return;
    if (id < 8128) {
        const float theta = mzi[2 * id], phi = mzi[2 * id + 1];
        float st, ct, sp, cp;
        sincosf(theta, &st, &ct);
        sincosf(phi, &sp, &cp);
        trig[id] = make_float4(ct * cp, ct * sp, st, 0.f);
    } else {
        trig[id] = make_float4(0.f, 0.f, 0.f, 0.f);  // pad (ring loads in-bounds)
    }
}

// ---------------- Kernel 1: build U, one block (1 wave) per row ----------------
// MZI id for (layer l, pair p): (127*l + (l&1))/2 + p   (max 8128 -> padded buf)
__global__ __launch_bounds__(64) void build_u(
    const float* __restrict__ oph, const float4* __restrict__ trig,
    unsigned short* ufrag /* 2 copies x 2 planes x 16384 bf16, frag order */) {
    const int r = blockIdx.x;   // row of U this block owns
    const int p = threadIdx.x;  // lane: owns cols 2p, 2p+1
    float2 c0 = make_float2((2 * p == r) ? 1.f : 0.f, 0.f);
    float2 c1 = make_float2((2 * p + 1 == r) ? 1.f : 0.f, 0.f);

    float4 ring[8];
    #pragma unroll
    for (int i = 0; i < 8; ++i)
        ring[i] = trig[(127 * i + (i & 1)) / 2 + p];

    #pragma unroll   // FULL unroll: ring indices constant -> ring stays in VGPRs
    for (int l = 0; l < 128; ++l) {
        const float4 t = ring[l & 7];
        if (l + 8 < 128)
            ring[l & 7] = trig[(127 * (l + 8) + ((l + 8) & 1)) / 2 + p];
        const float ar = t.x, ai = t.y, s = t.z;
        if ((l & 1) == 0) {
            // pair (2p, 2p+1) = (c0, c1), fully local
            const float2 u = c0, v = c1;
            c0.x = u.x * ar - u.y * ai + v.x * s;
            c0.y = u.x * ai + u.y * ar + v.y * s;
            c1.x = u.x * s - v.x * ar - v.y * ai;
            c1.y = u.y * s + v.x * ai - v.y * ar;
        } else {
            // pair q=p: cols (2p+1, 2p+2) = (my c1, lane p+1's c0)
            const float vx = __shfl_down(c0.x, 1);
            const float vy = __shfl_down(c0.y, 1);
            const float2 u = c1;
            const float nux = u.x * ar - u.y * ai + vx * s;
            const float nuy = u.x * ai + u.y * ar + vy * s;
            const float nvx = u.x * s - vx * ar - vy * ai;
            const float nvy = u.y * s + vx * ai - vy * ar;
            if (p < 63) { c1.x = nux; c1.y = nuy; }   // col 2p+1 update
            const float bx = __shfl_up(nvx, 1);       // col 2p+2 -> lane p+1's c0
            const float by = __shfl_up(nvy, 1);
            if (p > 0) { c0.x = bx; c0.y = by; }      // lane 0 keeps col 0
        }
    }

    // output-phase diagonal + bf16 + scatter into MFMA B-fragment order:
    // B[k][n]: nt=j>>4, lane=(j&15)|(((k>>3)&3)<<4), elem=k&7, kt=k>>5 (k=r,n=j)
    #pragma unroll
    for (int jj = 0; jj < 2; ++jj) {
        const int j = 2 * p + jj;
        const float2 v = (jj == 0) ? c0 : c1;
        float s, c;
        sincosf(oph[j], &s, &c);
        const unsigned short re = f2bf(v.x * c - v.y * s);
        const unsigned short im = f2bf(v.x * s + v.y * c);
        const int nt = j >> 4, kt = r >> 5;
        const int lane = (j & 15) | (((r >> 3) & 3) << 4);
        const int base = (nt * 4 + kt) * 512 + lane * 8 + (r & 7);
        ufrag[base]          = re;   // copy A, plane R
        ufrag[16384 + base]  = im;   // copy A, plane I
        ufrag[32768 + base]  = re;   // copy B, plane R
        ufrag[49152 + base]  = im;   // copy B, plane I
    }
}

// --------- 128-row tile, real-part GEMM (4 waves x 32 rows, N=K=128) ---------
__device__ __forceinline__ void gemm128(
    const float* __restrict__ fr, const float* __restrict__ fi,
    const unsigned short* ufcopy, float* out, int tilebase, int maxrow) {
    __shared__ __align__(16) unsigned short us[32768];  // 64 KB: Ur | Ui frags
    const int tid = threadIdx.x;
    {   // 64 KB global -> LDS: 256 thr x 16 iter x 16 B
        const uint4* g = (const uint4*)ufcopy;
        uint4* l = (uint4*)us;
        #pragma unroll
        for (int i = 0; i < 16; ++i) l[tid + 256 * i] = g[tid + 256 * i];
    }
    __syncthreads();

    const int wave = tid >> 6, lane = tid & 63;
    const int lm = lane & 15, lq = lane >> 4;
    const int rowbase = tilebase + wave * 32;

    float4v accR[2][8] = {};

    const size_t abase = (size_t)(rowbase + lm) * 128 + lq * 8;
    const float* pfr = fr + abase;   // mt adds 16 rows = +2048 floats
    const float* pfi = fi + abase;

    const short sgn = (short)0x8000;
    const short8 sgn8 = {sgn, sgn, sgn, sgn, sgn, sgn, sgn, sgn};

    float4v sr[2][2], si[2][2];
    #pragma unroll
    for (int mt = 0; mt < 2; ++mt) {
        sr[mt][0] = *(const float4v*)(pfr + mt * 2048);
        sr[mt][1] = *(const float4v*)(pfr + mt * 2048 + 4);
        si[mt][0] = *(const float4v*)(pfi + mt * 2048);
        si[mt][1] = *(const float4v*)(pfi + mt * 2048 + 4);
    }

    #pragma unroll
    for (int kt = 0; kt < 4; ++kt) {
        short8 afr[2], afin[2];
        #pragma unroll
        for (int mt = 0; mt < 2; ++mt) {
            afr[mt]  = pack8(sr[mt][0], sr[mt][1]);
            afin[mt] = pack8(si[mt][0], si[mt][1]) ^ sgn8;  // -Fi sign flip
        }
        if (kt < 3) {  // prefetch next k-tile while MFMAs run
            #pragma unroll
            for (int mt = 0; mt < 2; ++mt) {
                sr[mt][0] = *(const float4v*)(pfr + (kt + 1) * 32 + mt * 2048);
                sr[mt][1] = *(const float4v*)(pfr + (kt + 1) * 32 + mt * 2048 + 4);
                si[mt][0] = *(const float4v*)(pfi + (kt + 1) * 32 + mt * 2048);
                si[mt][1] = *(const float4v*)(pfi + (kt + 1) * 32 + mt * 2048 + 4);
            }
        }
        #pragma unroll
        for (int nt = 0; nt < 8; ++nt) {
            const int fo = (nt * 4 + kt) * 512 + lane * 8;
            const short8 ur = *(const short8*)&us[fo];
            const short8 ui = *(const short8*)&us[16384 + fo];
            #pragma unroll
            for (int mt = 0; mt < 2; ++mt) {
                accR[mt][nt] = MFMA(afr[mt],  ur, accR[mt][nt]);
                accR[mt][nt] = MFMA(afin[mt], ui, accR[mt][nt]);
            }
        }
    }

    // epilogue: D layout col = lane&15, row = (lane>>4)*4 + reg — GUARDED
    #pragma unroll
    for (int mt = 0; mt < 2; ++mt) {
        #pragma unroll
        for (int nt = 0; nt < 8; ++nt) {
            #pragma unroll
            for (int reg = 0; reg < 4; ++reg) {
                const int rr = rowbase + mt * 16 + lq * 4 + reg;
                if (rr < maxrow)
                    out[(size_t)rr * 128 + nt * 16 + lm] = accR[mt][nt][reg];
            }
        }
    }
}

__global__ __launch_bounds__(256, 2) void cgemm_main(
    const float* __restrict__ fr, const float* __restrict__ fi,
    const unsigned short* ufrag, float* out, int maxrow, int rowoff) {
    gemm128(fr, fi, ufrag, out, rowoff + blockIdx.x * 128, maxrow);  // copy A
}

__global__ __launch_bounds__(256, 2) void cgemm_tail(
    const float* __restrict__ fr, const float* __restrict__ fi,
    const unsigned short* ufrag, float* out, int maxrow) {
    // fallback path only: block b reads copy b, overwrites exactly its region
    gemm128(fr, fi, ufrag + blockIdx.x * 32768, out, blockIdx.x * 128, maxrow);
}

extern "C" void kernel_launch(void* const* d_in, const int* in_sizes, int n_in,
                              void* d_out, int out_size, void* d_ws, size_t ws_size,
                              hipStream_t stream) {
    const float* fr  = (const float*)d_in[0];
    const float* fi  = (const float*)d_in[1];
    const float* mzi = (const float*)d_in[2];
    const float* oph = (const float*)d_in[3];

    // Capacity in 128-float output rows; clamp by field rows (A-load safety).
    int maxrow = out_size / 128;
    const int arows = in_sizes[0] / 128;
    if (maxrow > arows) maxrow = arows;
    if (maxrow > 65536) maxrow = 65536;

    if (ws_size >= 262144) {
        // Preferred: stage in d_ws (R7 counters: ws ~256 MiB). No tail kernel.
        unsigned short* ufrag = (unsigned short*)d_ws;           // 128 KB (2 copies)
        float4* trig = (float4*)((char*)d_ws + 131072);          // 128 KB
        if (maxrow < 1) return;
        trig_k<<<32, 256, 0, stream>>>(mzi, trig);
        build_u<<<128, 64, 0, stream>>>(oph, trig, ufrag);
        const int nblk = (maxrow + 127) / 128;
        cgemm_main<<<nblk, 256, 0, stream>>>(fr, fi, ufrag, (float*)d_out,
                                             maxrow, 0);
    } else {
        // Fallback: stage inside d_out rows 0..511 (R5-R7 proven path).
        unsigned short* ufrag = (unsigned short*)d_out;          // rows 0..255
        float4* trig = (float4*)((float*)d_out + 32768);         // rows 256..511
        if (maxrow < 512) return;
        trig_k<<<32, 256, 0, stream>>>(mzi, trig);
        build_u<<<128, 64, 0, stream>>>(oph, trig, ufrag);
        const int nmain = (maxrow - 256 + 127) / 128;
        cgemm_main<<<nmain, 256, 0, stream>>>(fr, fi, ufrag, (float*)d_out,
                                              maxrow, 256);
        cgemm_tail<<<2, 256, 0, stream>>>(fr, fi, ufrag, (float*)d_out, maxrow);
    }
}